// Round 10
// baseline (452.346 us; speedup 1.0000x reference)
//
#include <hip/hip_runtime.h>
#include <hip/hip_fp16.h>
#include <math.h>

#define NNODES 50000
#define NEDGES 800000
#define D 128
#define NPB 4            // nodes per fused block
#define ROWS (NPB * 9)   // 36 token rows (permuted: 0-3 self, 4-35 aggregates)
#define MT 3             // 48-row B coverage (rows 36-47 zero pad)
#define TS 136           // tok/o16 row stride (halfs): 272 B
#define KS 264           // kv row stride (halfs): 528 B
#define OS 132           // oo row stride (floats)
#define CAPA 32          // primary bucket (64 B/node line)
#define CAPT 64          // total capacity incl. spill (Poisson(16): overflow P ~ 1e-15)
#define NPR (NNODES / 8) // 6250 nodes per range
#define SCHUNKS ((NEDGES + 1023) / 1024)          // 782 edge chunks (1024 edges each)
#define PREP_SLOTS (8192 + NNODES * D / 4)
#define PREP_BLOCKS ((PREP_SLOTS + 255) / 256)    // 6282
#define SCAT_BLOCKS (2 * 8 * SCHUNKS)             // 12512

typedef _Float16 half_t;
typedef half_t half2v __attribute__((ext_vector_type(2)));
typedef half_t half4 __attribute__((ext_vector_type(4)));
typedef half_t half8 __attribute__((ext_vector_type(8)));
typedef float floatx4 __attribute__((ext_vector_type(4)));
typedef unsigned short ushort_t;

// bucket reindex: node n -> idx = (n&7)*6250 + (n>>3); each range contiguous.

// ---- prep (weight swizzle + x->fp16) fused with XCD-local bucket scatter ----

__global__ __launch_bounds__(256) void prep_bucket_kernel(
    const float* __restrict__ w_in, const float* __restrict__ w_out,
    const float* __restrict__ x,
    const int* __restrict__ ei0, const int* __restrict__ ei1,
    half_t* __restrict__ w_swz, half_t* __restrict__ wo_swz,
    half_t* __restrict__ x16,
    int* __restrict__ cnt0, int* __restrict__ cnt1,
    ushort_t* __restrict__ A0, ushort_t* __restrict__ S0,
    ushort_t* __restrict__ A1, ushort_t* __restrict__ S1) {
  int b = blockIdx.x;
  if (b < PREP_BLOCKS) {
    int slot = b * 256 + threadIdx.x;
    if (slot < 8192) {  // weight swizzle
      const float* src;
      half_t* dst;
      int c, l;
      if (slot < 96 * 64) {
        c = slot >> 6; l = slot & 63;
        src = w_in; dst = w_swz + (size_t)slot * 8;
      } else {
        int s2 = slot - 96 * 64;
        c = s2 >> 6; l = s2 & 63;
        src = w_out; dst = wo_swz + (size_t)s2 * 8;
      }
      int nt = c >> 2, ks = c & 3;
      int n = nt * 16 + (l & 15);
      int kb = ks * 32 + (l >> 4) * 8;
#pragma unroll
      for (int j = 0; j < 8; ++j) dst[j] = (half_t)src[n * 128 + kb + j];
    } else {
      int idx = slot - 8192;
      if (idx < NNODES * D / 4) {
        float4 v = ((const float4*)x)[idx];
        union { half_t h[4]; uint2 u64; } p;
        p.h[0] = (half_t)v.x; p.h[1] = (half_t)v.y;
        p.h[2] = (half_t)v.z; p.h[3] = (half_t)v.w;
        ((uint2*)x16)[idx] = p.u64;
      }
    }
  } else {
    // scatter: range rng == blockIdx % 8 (XCD round-robin locality heuristic);
    // dst vector read first, src scalar loaded only on range match.
    int b2 = b - PREP_BLOCKS;
    int rng = (b2 + (PREP_BLOCKS & 7)) & 7;
    int pair = b2 >> 3;
    int set = (pair >= SCHUNKS);
    int chunk = set ? (pair - SCHUNKS) : pair;
    const int* ei = set ? ei1 : ei0;
    int* cnt = set ? cnt1 : cnt0;
    ushort_t* A = set ? A1 : A0;
    ushort_t* S = set ? S1 : S0;
    int ebase = chunk * 1024 + threadIdx.x * 4;
    if (ebase < NEDGES) {  // NEDGES % 4 == 0 -> int4 safe
      int4 dv = *(const int4*)(ei + NEDGES + ebase);
      int dd[4] = {dv.x, dv.y, dv.z, dv.w};
#pragma unroll
      for (int u = 0; u < 4; ++u) {
        int d = dd[u];
        if ((d & 7) == rng) {
          int s = ei[ebase + u];
          int idx = rng * NPR + (d >> 3);
          int pos = atomicAdd(&cnt[idx], 1);
          if (pos < CAPA) A[(size_t)idx * CAPA + pos] = (ushort_t)s;
          else if (pos < CAPT) S[(size_t)idx * CAPA + (pos - CAPA)] = (ushort_t)s;
        }
      }
    }
  }
}

// ---- fused gather + MFMA projection + attention + w_out + LN ----
// 4 nodes/block, 256 threads (4 waves). LDS ~25.5 KB -> 6 blocks/CU (24 waves).
// tok/kv share one LDS union: token fragments are register-hoisted, then a
// sync, then GEMM1 overwrites the region with k,v. Sum aggregated in packed
// fp16 (v_pk_add); sum token is stored without conversion.

__global__ __launch_bounds__(256, 6) void fused_attn_kernel(
    const half_t* __restrict__ x16,
    const int* __restrict__ cnt0, const ushort_t* __restrict__ A0,
    const ushort_t* __restrict__ S0,
    const int* __restrict__ cnt1, const ushort_t* __restrict__ A1,
    const ushort_t* __restrict__ S1,
    const half_t* __restrict__ w_swz, const half_t* __restrict__ wo_swz,
    const float* __restrict__ b_in, const float* __restrict__ b_out,
    const float* __restrict__ gamma, const float* __restrict__ beta,
    float* __restrict__ out) {
  // layout: bufS (tok 48xTS | kv 36xKS union) 19008 B @0
  //         o16 16xTS halfs 4352 B @19008
  //         qoo union (qS 4xTS halfs | oo 4xOS floats) 2112 B @23360
  //         scS 576 B @25472 ; cntS 32 B @26048
  __shared__ __align__(16) char smem[26080];
  half_t* bufS = (half_t*)smem;
  half_t* o16 = (half_t*)(smem + 19008);
  half_t* qS = (half_t*)(smem + 23360);
  float* oo = (float*)(smem + 23360);
  float (*scS)[4][9] = (float(*)[4][9])(smem + 25472);
  int (*cntS)[2] = (int(*)[2])(smem + 26048);

  const int tid = threadIdx.x;
  const int lane = tid & 63, wv = tid >> 6;
  const int quad = lane >> 4, l15 = lane & 15;
  const int slot = quad;      // gather row slot 0..3
  const int d16 = l15;        // gather dim block (8 dims)
  const int node = blockIdx.x * NPB + wv;
  const int nidx = (node & 7) * NPR + (node >> 3);

  // zero tok pad rows 36-47 and o16 pad rows 4-15
  for (int i = tid; i < 12 * (TS / 2); i += 256)
    ((uint*)(bufS + 36 * TS))[i] = 0u;
  for (int i = tid; i < 12 * (TS / 2); i += 256)
    ((uint*)(o16 + 4 * TS))[i] = 0u;

  // --- counts + bucket entries (lane holds entry `lane`; spill read only if needed) ---
  int c0 = cnt0[nidx]; c0 = c0 > CAPT ? CAPT : c0;
  int c1 = cnt1[nidx]; c1 = c1 > CAPT ? CAPT : c1;
  if (lane == 0) { cntS[wv][0] = c0; cntS[wv][1] = c1; }
  int ent0 = 0, ent1 = 0;
  if (lane < CAPA) {
    ent0 = A0[(size_t)nidx * CAPA + lane];
    ent1 = A1[(size_t)nidx * CAPA + lane];
  } else {
    if (c0 > CAPA) ent0 = S0[(size_t)nidx * CAPA + (lane - CAPA)];
    if (c1 > CAPA) ent1 = S1[(size_t)nidx * CAPA + (lane - CAPA)];
  }
  uint selfw = ((const uint*)(x16 + (size_t)node * 128))[lane];

  // --- gather ---
  {
    half2v mxA[4], mnA[4], smA[4], mxB[4], mnB[4], smB[4];
    const half_t NINF = (half_t)(-INFINITY), PINF = (half_t)INFINITY;
    const half2v Z2 = (half2v){(half_t)0.f, (half_t)0.f};
#pragma unroll
    for (int p = 0; p < 4; ++p) {
      mxA[p] = (half2v){NINF, NINF}; mnA[p] = (half2v){PINF, PINF}; smA[p] = Z2;
      mxB[p] = (half2v){NINF, NINF}; mnB[p] = (half2v){PINF, PINF}; smB[p] = Z2;
    }

    auto issue4 = [&](int entv, int c, int j, uint4* rv, int* val) {
#pragma unroll
      for (int u = 0; u < 4; ++u) {
        int r = j + u * 4 + slot;
        int rc = (r < c) ? r : (c - 1);
        int src = __shfl(entv, rc);
        rv[u] = *(const uint4*)(x16 + (size_t)src * 128 + d16 * 8);
        val[u] = (r < c);
      }
    };
    auto accum4 = [&](const uint4* rv, const int* val, half2v* mx2, half2v* mn2,
                      half2v* sm2) {
#pragma unroll
      for (int u = 0; u < 4; ++u) {
        union { uint4 q; half2v p2[4]; } cc;
        cc.q = rv[u];
        bool v = val[u] != 0;
#pragma unroll
        for (int p = 0; p < 4; ++p) {
          mx2[p] = __builtin_elementwise_max(mx2[p], cc.p2[p]);
          mn2[p] = __builtin_elementwise_min(mn2[p], cc.p2[p]);
          sm2[p] = sm2[p] + (v ? cc.p2[p] : Z2);  // v_pk_add + cndmask
        }
      }
    };

    uint4 rva[4], rvb[4];
    int wa[4], wb[4];
    if (c0 > 0) issue4(ent0, c0, 0, rva, wa);
    if (c1 > 0) issue4(ent1, c1, 0, rvb, wb);   // 8 loads in flight
    if (c0 > 0) accum4(rva, wa, mxA, mnA, smA);
    if (c1 > 0) accum4(rvb, wb, mxB, mnB, smB);
    for (int j = 16; j < c0; j += 16) { issue4(ent0, c0, j, rva, wa); accum4(rva, wa, mxA, mnA, smA); }
    for (int j = 16; j < c1; j += 16) { issue4(ent1, c1, j, rvb, wb); accum4(rvb, wb, mxB, mnB, smB); }

    // cross-slot reduce + write (slots 16 lanes apart), per set
    union HB { half2v h; int i; };
    auto finish = [&](int c, half2v* mx2, half2v* mn2, half2v* sm2, int set) {
#pragma unroll
      for (int p = 0; p < 4; ++p) {
        HB a, b;
        a.h = mx2[p];
        b.i = __shfl_xor(a.i, 16); a.h = __builtin_elementwise_max(a.h, b.h);
        b.i = __shfl_xor(a.i, 32); a.h = __builtin_elementwise_max(a.h, b.h);
        mx2[p] = a.h;
        a.h = mn2[p];
        b.i = __shfl_xor(a.i, 16); a.h = __builtin_elementwise_min(a.h, b.h);
        b.i = __shfl_xor(a.i, 32); a.h = __builtin_elementwise_min(a.h, b.h);
        mn2[p] = a.h;
        a.h = sm2[p];
        b.i = __shfl_xor(a.i, 16); a.h = a.h + b.h;
        b.i = __shfl_xor(a.i, 32); a.h = a.h + b.h;
        sm2[p] = a.h;
      }
      float inv = 1.f / (float)(c > 1 ? c : 1);
      union { uint4 q; half2v p2[4]; half_t h[8]; } o, s;
#pragma unroll
      for (int p = 0; p < 4; ++p) s.p2[p] = sm2[p];
      if (slot == 0) {
#pragma unroll
        for (int p = 0; p < 4; ++p) o.p2[p] = mx2[p];
      } else if (slot == 1) {
#pragma unroll
        for (int p = 0; p < 4; ++p) o.p2[p] = mn2[p];
      } else if (slot == 2) {
        o.q = s.q;  // sum token is the packed fp16 sums directly
      } else {
#pragma unroll
        for (int e = 0; e < 8; ++e) o.h[e] = (half_t)((float)s.h[e] * inv);
      }
      if (c == 0) o.q = make_uint4(0, 0, 0, 0);
      *(uint4*)(bufS + (size_t)(4 + wv * 8 + 4 * set + slot) * TS + d16 * 8) = o.q;
    };
    finish(c0, mxA, mnA, smA, 0);
    finish(c1, mxB, mnB, smB, 1);

    // self token -> row wv
    ((uint*)(bufS + wv * TS))[lane] = selfw;
  }
  __syncthreads();

  // GEMM1 (transposed): hoist ALL token B-frags to regs, sync (tok region then
  // dead), then MFMA + write k,v into the SAME region with kv layout.
  {
    half8 tb[MT][4];
#pragma unroll
    for (int mt = 0; mt < MT; ++mt)
#pragma unroll
      for (int ks = 0; ks < 4; ++ks)
        tb[mt][ks] = *(const half8*)(bufS + (mt * 16 + l15) * TS + ks * 32 + quad * 8);
    __syncthreads();  // all token reads done; bufS reusable as kv

    for (int ntb = 0; ntb < 6; ++ntb) {
      int nt = wv + ntb * 4;  // 24 n-tiles over 4 waves; nt<8 = q cols
      half8 aw[4];
#pragma unroll
      for (int ks = 0; ks < 4; ++ks)
        aw[ks] = *(const half8*)(w_swz + ((size_t)(nt * 4 + ks) * 64 + lane) * 8);
      int col0 = nt * 16 + quad * 4;
      float4 bias = *(const float4*)(b_in + col0);
#pragma unroll
      for (int mt = 0; mt < MT; ++mt) {
        if (nt >= 8 || mt == 0) {
          floatx4 acc = {0.f, 0.f, 0.f, 0.f};
#pragma unroll
          for (int ks = 0; ks < 4; ++ks)
            acc = __builtin_amdgcn_mfma_f32_16x16x32_f16(aw[ks], tb[mt][ks], acc, 0, 0, 0);
          half4 hv = {(half_t)(acc[0] + bias.x), (half_t)(acc[1] + bias.y),
                      (half_t)(acc[2] + bias.z), (half_t)(acc[3] + bias.w)};
          int row = mt * 16 + l15;  // token row
          if (nt < 8) {
            if (l15 < 4) *(half4*)(qS + l15 * TS + col0) = hv;  // self rows only
          } else {
            if (row < ROWS) *(half4*)(bufS + row * KS + (col0 - 128)) = hv;
          }
        }
      }
    }
  }
  __syncthreads();

  // scores: wave wv = node; lane -> (h = lane>>4, t = lane&15), t<9 active
  {
    int h = lane >> 4, t = lane & 15;
    if (t < 9) {
      float sc = -1e30f;
      bool masked = (t >= 1) && (cntS[wv][(t - 1) >> 2] == 0);
      if (!masked) {
        int krow = (t == 0) ? wv : (4 + wv * 8 + (t - 1));
        const half8* qp = (const half8*)(qS + wv * TS + h * 32);
        const half8* kp = (const half8*)(bufS + krow * KS + h * 32);
        float acc = 0.f;
#pragma unroll
        for (int i = 0; i < 4; ++i) {
          half8 qv = qp[i], kv = kp[i];
#pragma unroll
          for (int jj = 0; jj < 8; ++jj) acc += (float)qv[jj] * (float)kv[jj];
        }
        sc = acc * 0.17677669529663687f;  // 1/sqrt(32)
      }
      scS[wv][h][t] = sc;
    }
  }
  __syncthreads();

  if (lane < 4) {  // softmax per (node=wv, head=lane)
    int h = lane;
    float m = -INFINITY;
#pragma unroll
    for (int t = 0; t < 9; ++t) m = fmaxf(m, scS[wv][h][t]);
    float ev[9], sum = 0.f;
#pragma unroll
    for (int t = 0; t < 9; ++t) { ev[t] = __expf(scS[wv][h][t] - m); sum += ev[t]; }
    float inv = 1.f / sum;
#pragma unroll
    for (int t = 0; t < 9; ++t) scS[wv][h][t] = ev[t] * inv;
  }
  __syncthreads();

  // PV: o16 row wv (node) = sum_t attn * v
  {
#pragma unroll
    for (int u = 0; u < 2; ++u) {
      int d2 = lane + 64 * u;
      int h = d2 >> 5;
      float acc = 0.f;
#pragma unroll
      for (int t = 0; t < 9; ++t) {
        int vrow = (t == 0) ? wv : (4 + wv * 8 + (t - 1));
        acc += scS[wv][h][t] * (float)bufS[vrow * KS + 128 + d2];
      }
      o16[wv * TS + d2] = (half_t)acc;
    }
  }
  __syncthreads();

  // GEMM2 (transposed): oo[node][128] = o16 @ w_out^T + b_out (oo overlays dead qS)
  {
    half8 ob[4];
#pragma unroll
    for (int ks = 0; ks < 4; ++ks)
      ob[ks] = *(const half8*)(o16 + l15 * TS + ks * 32 + quad * 8);
#pragma unroll
    for (int ntb = 0; ntb < 2; ++ntb) {
      int nt = wv + ntb * 4;
      half8 aw[4];
#pragma unroll
      for (int ks = 0; ks < 4; ++ks)
        aw[ks] = *(const half8*)(wo_swz + ((size_t)(nt * 4 + ks) * 64 + lane) * 8);
      floatx4 acc = {0.f, 0.f, 0.f, 0.f};
#pragma unroll
      for (int ks = 0; ks < 4; ++ks)
        acc = __builtin_amdgcn_mfma_f32_16x16x32_f16(aw[ks], ob[ks], acc, 0, 0, 0);
      int col0 = nt * 16 + quad * 4;
      float4 bias = *(const float4*)(b_out + col0);
      if (l15 < 4) {
        float4 r;
        r.x = acc[0] + bias.x; r.y = acc[1] + bias.y;
        r.z = acc[2] + bias.z; r.w = acc[3] + bias.w;
        *(float4*)(oo + l15 * OS + col0) = r;
      }
    }
  }
  __syncthreads();

  // LayerNorm per node (wave wv = node; lane covers 2 cols)
  {
    float v[2];
    float sum = 0.f, sq = 0.f;
#pragma unroll
    for (int u = 0; u < 2; ++u) {
      int c = lane + 64 * u;
      v[u] = oo[wv * OS + c];
      sum += v[u];
      sq += v[u] * v[u];
    }
#pragma unroll
    for (int m = 1; m < 64; m <<= 1) {
      sum += __shfl_xor(sum, m);
      sq += __shfl_xor(sq, m);
    }
    float mu = sum * (1.f / 128.f);
    float var = sq * (1.f / 128.f) - mu * mu;
    float rs = rsqrtf(var + 1e-5f);
#pragma unroll
    for (int u = 0; u < 2; ++u) {
      int c = lane + 64 * u;
      out[(size_t)node * 128 + c] = (v[u] - mu) * rs * gamma[c] + beta[c];
    }
  }
}

// ---------------- launch ----------------

extern "C" void kernel_launch(void* const* d_in, const int* in_sizes, int n_in,
                              void* d_out, int out_size, void* d_ws, size_t ws_size,
                              hipStream_t stream) {
  const float* x = (const float*)d_in[0];
  const int* ei0 = (const int*)d_in[1];
  const int* ei1 = (const int*)d_in[2];
  const float* w_in = (const float*)d_in[3];
  const float* b_in = (const float*)d_in[4];
  const float* w_out = (const float*)d_in[5];
  const float* b_out = (const float*)d_in[6];
  const float* gamma = (const float*)d_in[7];
  const float* beta = (const float*)d_in[8];
  float* out = (float*)d_out;

  char* wsB = (char*)d_ws;
  size_t off = 0;
  int* cnt0 = (int*)(wsB + off); off += (size_t)NNODES * 4;
  int* cnt1 = (int*)(wsB + off); off += (size_t)NNODES * 4;
  ushort_t* A0 = (ushort_t*)(wsB + off); off += (size_t)NNODES * CAPA * 2;
  ushort_t* A1 = (ushort_t*)(wsB + off); off += (size_t)NNODES * CAPA * 2;
  ushort_t* S0 = (ushort_t*)(wsB + off); off += (size_t)NNODES * CAPA * 2;
  ushort_t* S1 = (ushort_t*)(wsB + off); off += (size_t)NNODES * CAPA * 2;
  off = (off + 15) & ~(size_t)15;
  half_t* w_swz = (half_t*)(wsB + off);  off += (size_t)96 * 64 * 8 * 2;
  half_t* wo_swz = (half_t*)(wsB + off); off += (size_t)32 * 64 * 8 * 2;
  half_t* x16 = (half_t*)(wsB + off);    off += (size_t)NNODES * 128 * 2;

  hipMemsetAsync(cnt0, 0, 2 * NNODES * sizeof(int), stream);

  prep_bucket_kernel<<<PREP_BLOCKS + SCAT_BLOCKS, 256, 0, stream>>>(
      w_in, w_out, x, ei0, ei1, w_swz, wo_swz, x16, cnt0, cnt1, A0, S0, A1, S1);
  fused_attn_kernel<<<NNODES / NPB, 256, 0, stream>>>(x16, cnt0, A0, S0, cnt1, A1, S1,
                                                      w_swz, wo_swz, b_in, b_out,
                                                      gamma, beta, out);
}